// Round 3
// baseline (113.957 us; speedup 1.0000x reference)
//
#include <hip/hip_runtime.h>
#include <stdint.h>

// Problem constants (fixed by reference setup_inputs)
#define B_      8
#define N_      48
#define M_      (N_ * N_)       // 2304 vectors per batch
#define ROWS    12              // rows of the pair matrix per block (regs: 3*12+temps < 64)
#define CPB     (M_ / ROWS)     // 192 chunks per batch
#define NBLK    (B_ * CPB)      // 1536 blocks = exactly 6 per CU, one round at 8/CU capacity
#define TPB     256
#define KITER   (M_ / TPB)      // 9 column iterations

// ws layout
#define WS_PARTS_OFF   0                          // float  partS[NBLK]
#define WS_PARTC_OFF   (NBLK * sizeof(float))     // uint   partC[NBLK]
#define WS_TICKET_OFF  (2 * NBLK * sizeof(float)) // uint   ticket

// Single fused kernel: each block = (batch, 12-row chunk). Builds the
// per-batch (vx,vy) table in LDS (float2 -> 18.4 KB, 2-way bank aliasing =
// free), sweeps all 12 rows in ONE pass over the 2304 columns (each
// ds_read_b64 reused 12x), recomputing 1/norm per column with rsqrt.
// Last-finishing block (threadfence+ticket) reduces the 1536 partials in
// double and writes the final scalar.
//
// amdgpu_waves_per_eu(6,8): R2's __launch_bounds__(256,4) let the backend
// target 8 waves/EU with 64 VGPRs and spill ~30 regs to scratch (14 MB
// scratch WRITE_SIZE). Pinning the range to what the code actually fits
// (~60 regs) kills the spills while keeping 8 waves/EU possible.
__global__ __launch_bounds__(TPB)
__attribute__((amdgpu_waves_per_eu(6, 8)))
void fused_kernel(
    const float* __restrict__ gt,    // [B, 48, 2]
    const float* __restrict__ sm,    // [B, 48, 48]
    const float* __restrict__ thrp,  // [1]
    float* __restrict__ partS,
    unsigned int* __restrict__ partC,
    unsigned int* __restrict__ ticket,
    float* __restrict__ out)
{
    __shared__ float2 tile[M_];      // (vx, vy) : 18432 B
    __shared__ float  gx[N_], gy[N_];
    __shared__ float  redS[4];
    __shared__ unsigned int redC[4];
    __shared__ int amLast;

    const int tid   = threadIdx.x;
    const int b     = blockIdx.x / CPB;
    const int chunk = blockIdx.x - b * CPB;

    if (tid < N_) {
        float2 g = ((const float2*)gt)[b * N_ + tid];
        gx[tid] = g.x;
        gy[tid] = g.y;
    }
    __syncthreads();

    const float thr = thrp[0];
    // Build vector table: v = (gt[i]-gt[j]) * sm_thresholded
    for (int idx = tid; idx < M_; idx += TPB) {   // 9 iterations
        float s = sm[b * M_ + idx];
        s = (s < thr) ? 0.0f : s;
        int i = idx / N_;
        int j = idx - i * N_;
        // exact IEEE single ops; matches numpy's (gt_i - gt_j) * sm
        float vx = __fmul_rn(__fsub_rn(gx[i], gx[j]), s);
        float vy = __fmul_rn(__fsub_rn(gy[i], gy[j]), s);
        tile[idx] = make_float2(vx, vy);
    }
    __syncthreads();

    const int m0 = chunk * ROWS;
    float rx[ROWS], ry[ROWS], acc[ROWS];
    #pragma unroll
    for (int r = 0; r < ROWS; ++r) {
        float2 t = tile[m0 + r];   // wave-uniform LDS broadcast (free)
        rx[r] = t.x; ry[r] = t.y; acc[r] = 0.0f;
    }

    unsigned int cnt = 0;
    for (int k = 0; k < KITER; ++k) {
        const float2 c = tile[tid + k * TPB];  // ds_read_b64, 2-way aliasing = free
        // column 1/norm recomputed (frees the .z slot; rsqrt 1x per 12 rows)
        const float w = rsqrtf(fmaf(c.x, c.x, fmaf(c.y, c.y, 2e-9f)));
        #pragma unroll
        for (int r = 0; r < ROWS; ++r) {
            // discrete mul/mul/add (no fma contraction) so the exact-zero
            // count matches the fp32 reference semantics (absmax was 0.0)
            float d = __fadd_rn(__fmul_rn(rx[r], c.x), __fmul_rn(ry[r], c.y));
            cnt += (d != 0.0f) ? 1u : 0u;
            acc[r] = fmaf(fabsf(d), w, acc[r]);  // |d| folds into VOP3 abs modifier
        }
    }

    float total = 0.0f;
    #pragma unroll
    for (int r = 0; r < ROWS; ++r) {
        // hoisted row-norm factor, recomputed once per row (saves rw[] regs)
        float wm = rsqrtf(fmaf(rx[r], rx[r], fmaf(ry[r], ry[r], 2e-9f)));
        total = fmaf(acc[r], wm, total);
    }

    // wave64 shuffle reduce, then cross-wave via LDS
    for (int off = 32; off > 0; off >>= 1) {
        total += __shfl_down(total, off, 64);
        cnt   += __shfl_down(cnt,   off, 64);
    }
    const int wave = tid >> 6;
    if ((tid & 63) == 0) { redS[wave] = total; redC[wave] = cnt; }
    __syncthreads();
    if (tid == 0) {
        partS[blockIdx.x] = redS[0] + redS[1] + redS[2] + redS[3];
        partC[blockIdx.x] = redC[0] + redC[1] + redC[2] + redC[3];
        // release: make partials visible device-wide, then take a ticket
        __threadfence();
        unsigned int t = atomicAdd(ticket, 1u);
        amLast = (t == NBLK - 1) ? 1 : 0;
    }
    __syncthreads();

    if (amLast) {
        __threadfence();   // acquire: see all blocks' partials
        __shared__ double rs[4], rc[4];
        double s = 0.0, c = 0.0;
        for (int i = tid; i < NBLK; i += TPB) {   // 6 iterations
            s += (double)partS[i];
            c += (double)partC[i];
        }
        for (int off = 32; off > 0; off >>= 1) {
            s += __shfl_down(s, off, 64);
            c += __shfl_down(c, off, 64);
        }
        if ((tid & 63) == 0) { rs[wave] = s; rc[wave] = c; }
        __syncthreads();
        if (tid == 0)
            out[0] = (float)((rs[0] + rs[1] + rs[2] + rs[3]) /
                             (rc[0] + rc[1] + rc[2] + rc[3]));
    }
}

extern "C" void kernel_launch(void* const* d_in, const int* in_sizes, int n_in,
                              void* d_out, int out_size, void* d_ws, size_t ws_size,
                              hipStream_t stream) {
    const float* gt  = (const float*)d_in[0];   // [8,48,2]
    const float* sm  = (const float*)d_in[1];   // [8,48,48]
    const float* thr = (const float*)d_in[2];   // [1]

    float*        partS  = (float*)((char*)d_ws + WS_PARTS_OFF);
    unsigned int* partC  = (unsigned int*)((char*)d_ws + WS_PARTC_OFF);
    unsigned int* ticket = (unsigned int*)((char*)d_ws + WS_TICKET_OFF);

    // zero the ticket (ws is poisoned to 0xAA before every launch)
    hipMemsetAsync(ticket, 0, sizeof(unsigned int), stream);
    fused_kernel<<<NBLK, TPB, 0, stream>>>(gt, sm, thr, partS, partC, ticket,
                                           (float*)d_out);
}

// Round 4
// 70.351 us; speedup vs baseline: 1.6198x; 1.6198x over previous
//
#include <hip/hip_runtime.h>
#include <stdint.h>

// Problem constants (fixed by reference setup_inputs)
#define B_      8
#define N_      48
#define M_      (N_ * N_)       // 2304 vectors per batch
#define RPB     16              // rows per block (4 passes of 4)
#define CHUNKS  (M_ / RPB)      // 144
#define NBLK    (B_ * CHUNKS)   // 1152 blocks; 5/CU resident -> whole grid in one round
#define TPB     256
#define KITER   (M_ / TPB)      // 9 column iterations per pass

// ws layout
#define WS_PARTS_OFF   0                          // float partS[NBLK]
#define WS_PARTC_OFF   (NBLK * sizeof(float))     // uint  partC[NBLK]

// Lessons burned in from R2/R3: NO occupancy attributes (amdgpu_waves_per_eu
// and __launch_bounds__(.,minwaves) both made the allocator spill the row
// arrays to scratch: 14-46 MB of scratch traffic, VALUBusy 13-19%). Keep the
// live set tiny by construction instead: 4 rows per pass (~30 live VGPRs).
__global__ __launch_bounds__(TPB) void pair_kernel(
    const float* __restrict__ gt,    // [B, 48, 2]
    const float* __restrict__ sm,    // [B, 48, 48]
    const float* __restrict__ thrp,  // [1]
    float* __restrict__ partS,
    unsigned int* __restrict__ partC)
{
    // SoA: float2 (2-way bank aliasing = free) + separate w array (b32,
    // 2-way = free). float4 AoS was a 4-way conflict (R2: 49k conflicts).
    __shared__ float2 vxy[M_];       // 18432 B
    __shared__ float  vw[M_];        //  9216 B  (w = rsqrt(|v|^2 + 2e-9), built once)
    __shared__ float  gx[N_], gy[N_];
    __shared__ float  redS[4];
    __shared__ unsigned int redC[4];

    const int tid   = threadIdx.x;
    const int b     = blockIdx.x / CHUNKS;
    const int chunk = blockIdx.x - b * CHUNKS;

    if (tid < N_) {
        float2 g = ((const float2*)gt)[b * N_ + tid];
        gx[tid] = g.x;
        gy[tid] = g.y;
    }
    __syncthreads();

    const float thr = thrp[0];
    // Build vector table: v = (gt[i]-gt[j]) * sm_thresholded
    for (int idx = tid; idx < M_; idx += TPB) {   // 9 iterations
        float s = sm[b * M_ + idx];
        s = (s < thr) ? 0.0f : s;
        int i = idx / N_;
        int j = idx - i * N_;
        // exact IEEE single ops; matches numpy's (gt_i - gt_j) * sm
        float vx = __fmul_rn(__fsub_rn(gx[i], gx[j]), s);
        float vy = __fmul_rn(__fsub_rn(gy[i], gy[j]), s);
        vxy[idx] = make_float2(vx, vy);
        vw[idx]  = rsqrtf(fmaf(vx, vx, fmaf(vy, vy, 2e-9f)));
    }
    __syncthreads();

    const int m0 = chunk * RPB;
    float total = 0.0f;
    unsigned int cnt = 0;

    // 4 passes x 4 rows: live set = rx/ry/acc[4] + column temps ~ 30 VGPRs.
    #pragma unroll
    for (int g = 0; g < RPB / 4; ++g) {
        float rx0, ry0, rx1, ry1, rx2, ry2, rx3, ry3;
        {
            float2 t0 = vxy[m0 + g * 4 + 0];   // wave-uniform broadcast (free)
            float2 t1 = vxy[m0 + g * 4 + 1];
            float2 t2 = vxy[m0 + g * 4 + 2];
            float2 t3 = vxy[m0 + g * 4 + 3];
            rx0 = t0.x; ry0 = t0.y; rx1 = t1.x; ry1 = t1.y;
            rx2 = t2.x; ry2 = t2.y; rx3 = t3.x; ry3 = t3.y;
        }
        float a0 = 0.0f, a1 = 0.0f, a2 = 0.0f, a3 = 0.0f;
        for (int k = 0; k < KITER; ++k) {      // 9 iterations
            const int n = tid + k * TPB;
            const float2 c = vxy[n];           // ds_read_b64, reused x4 rows
            const float  w = vw[n];            // ds_read_b32
            // discrete mul/mul/add (no fma contraction) so the exact-zero
            // count matches the fp32 reference semantics (absmax was 0.0)
            float d0 = __fadd_rn(__fmul_rn(rx0, c.x), __fmul_rn(ry0, c.y));
            float d1 = __fadd_rn(__fmul_rn(rx1, c.x), __fmul_rn(ry1, c.y));
            float d2 = __fadd_rn(__fmul_rn(rx2, c.x), __fmul_rn(ry2, c.y));
            float d3 = __fadd_rn(__fmul_rn(rx3, c.x), __fmul_rn(ry3, c.y));
            cnt += (d0 != 0.0f) ? 1u : 0u;
            cnt += (d1 != 0.0f) ? 1u : 0u;
            cnt += (d2 != 0.0f) ? 1u : 0u;
            cnt += (d3 != 0.0f) ? 1u : 0u;
            a0 = fmaf(fabsf(d0), w, a0);       // |d| folds into VOP3 abs modifier
            a1 = fmaf(fabsf(d1), w, a1);
            a2 = fmaf(fabsf(d2), w, a2);
            a3 = fmaf(fabsf(d3), w, a3);
        }
        // hoisted row-norm factor (read once from LDS, broadcast)
        total = fmaf(a0, vw[m0 + g * 4 + 0], total);
        total = fmaf(a1, vw[m0 + g * 4 + 1], total);
        total = fmaf(a2, vw[m0 + g * 4 + 2], total);
        total = fmaf(a3, vw[m0 + g * 4 + 3], total);
    }

    // wave64 shuffle reduce, then cross-wave via LDS
    for (int off = 32; off > 0; off >>= 1) {
        total += __shfl_down(total, off, 64);
        cnt   += __shfl_down(cnt,   off, 64);
    }
    const int wave = tid >> 6;
    if ((tid & 63) == 0) { redS[wave] = total; redC[wave] = cnt; }
    __syncthreads();
    if (tid == 0) {
        partS[blockIdx.x] = redS[0] + redS[1] + redS[2] + redS[3];
        partC[blockIdx.x] = redC[0] + redC[1] + redC[2] + redC[3];
    }
}

// Kernel 2: reduce the 1152 block partials (double accumulation) and divide.
// Cross-dispatch visibility is guaranteed by the stream's dispatch-boundary
// release/acquire (R1 passed with absmax 0.0 using this structure).
__global__ __launch_bounds__(256) void finalize_kernel(
    const float* __restrict__ partS,
    const unsigned int* __restrict__ partC,
    float* __restrict__ out)
{
    __shared__ double rs[4];
    __shared__ double rc[4];
    const int tid = threadIdx.x;
    double s = 0.0, c = 0.0;
    for (int i = tid; i < NBLK; i += 256) {
        s += (double)partS[i];
        c += (double)partC[i];
    }
    for (int off = 32; off > 0; off >>= 1) {
        s += __shfl_down(s, off, 64);
        c += __shfl_down(c, off, 64);
    }
    const int wave = tid >> 6;
    if ((tid & 63) == 0) { rs[wave] = s; rc[wave] = c; }
    __syncthreads();
    if (tid == 0) {
        out[0] = (float)((rs[0] + rs[1] + rs[2] + rs[3]) /
                         (rc[0] + rc[1] + rc[2] + rc[3]));
    }
}

extern "C" void kernel_launch(void* const* d_in, const int* in_sizes, int n_in,
                              void* d_out, int out_size, void* d_ws, size_t ws_size,
                              hipStream_t stream) {
    const float* gt  = (const float*)d_in[0];   // [8,48,2]
    const float* sm  = (const float*)d_in[1];   // [8,48,48]
    const float* thr = (const float*)d_in[2];   // [1]

    float*        partS = (float*)((char*)d_ws + WS_PARTS_OFF);
    unsigned int* partC = (unsigned int*)((char*)d_ws + WS_PARTC_OFF);

    pair_kernel<<<NBLK, TPB, 0, stream>>>(gt, sm, thr, partS, partC);
    finalize_kernel<<<1, 256, 0, stream>>>(partS, partC, (float*)d_out);
}